// Round 1
// 150.257 us; speedup vs baseline: 1.0030x; 1.0030x over previous
//
#include <hip/hip_runtime.h>

#define NCHAN 12
#define NBINS 2200
#define HMIN  (-1200.0f)
#define HMAX  (1000.0f)
#define SLICE_ELEMS 65536      // 256*256, one (batch, channel) slab
#define SPLIT 2                // blocks per slab -> 768 blocks = exactly 3/CU
#define BLOCK 256

// Kernel 1: out = hist_counts (WRITE, not add — d_out is poisoned 0xAA).
// float4-vectorized; scalar tail for generality.
__global__ __launch_bounds__(BLOCK)
void init_out(const float* __restrict__ hist, float* __restrict__ out, int n) {
    int i = (blockIdx.x * BLOCK + threadIdx.x) * 4;
    if (i + 3 < n) {
        *(float4*)(out + i) = *(const float4*)(hist + i);
    } else {
        for (; i < n; ++i) out[i] = hist[i];
    }
}

__device__ __forceinline__ void bin4(const float4 v, unsigned int* lh) {
    float vals[4] = {v.x, v.y, v.z, v.w};
#pragma unroll
    for (int j = 0; j < 4; ++j) {
        // Bin width is exactly 1.0f (2200 bins over [-1200, 1000]), so
        // bin = floor(f + 1200).  For t >= 0, (int)t truncation == floor.
        // t >= 0.0f  <=>  f >= -1200.0f in fp32 (boundary rounding checked:
        // the largest fp32 below -1200 gives t = -1.22e-4, strictly < 0).
        // NaN fails t >= 0.  f == 1000 -> t = 2200 -> min -> last bin,
        // matching torch.histc.
        float t = vals[j] + 1200.0f;
        if (t >= 0.0f && vals[j] <= HMAX) {
            int idx = min((int)t, NBINS - 1);
            atomicAdd(&lh[idx], 1u);
        }
    }
}

// Kernel 2: per-block private LDS histogram over one slab chunk, then
// global float atomicAdd flush into out[c*NBINS + bin].
__global__ __launch_bounds__(BLOCK)
void hist_kernel(const float* __restrict__ x, float* __restrict__ out) {
    __shared__ unsigned int lh[NBINS];
    for (int i = threadIdx.x; i < NBINS; i += BLOCK) lh[i] = 0u;
    __syncthreads();

    const int slice = blockIdx.x / SPLIT;     // = b*NCHAN + c (layout [B,C,H,W])
    const int sub   = blockIdx.x % SPLIT;
    const int c     = slice % NCHAN;
    const int chunk = SLICE_ELEMS / SPLIT;    // 32768 elements per block

    const float4* __restrict__ xp =
        (const float4*)(x + (long long)slice * SLICE_ELEMS + (long long)sub * chunk);

    // chunk/4 = 8192 float4 = 4 outer iters x (256 threads x 8 loads).
    // Exact fit: 8192 == 4 * BLOCK * 8, so no bounds check needed.
    // 8 independent 16B loads in flight/thread hides HBM latency past the
    // LDS-atomic binning.
#pragma unroll
    for (int k = 0; k < 4; ++k) {
        const int base = threadIdx.x + k * (BLOCK * 8);
        float4 v[8];
#pragma unroll
        for (int u = 0; u < 8; ++u) v[u] = xp[base + u * BLOCK];
#pragma unroll
        for (int u = 0; u < 8; ++u) bin4(v[u], lh);
    }
    __syncthreads();

    float* __restrict__ outc = out + c * NBINS;
    for (int i = threadIdx.x; i < NBINS; i += BLOCK) {
        unsigned int v = lh[i];
        if (v) atomicAdd(&outc[i], (float)v);  // integer-valued, exact in fp32
    }
}

extern "C" void kernel_launch(void* const* d_in, const int* in_sizes, int n_in,
                              void* d_out, int out_size, void* d_ws, size_t ws_size,
                              hipStream_t stream) {
    const float* x    = (const float*)d_in[0];
    const float* hist = (const float*)d_in[1];
    float* out        = (float*)d_out;

    // 1) out = hist_counts  (out_size = 26400 elements; float4 path)
    int nvec = (out_size + 3) / 4;
    int nblk = (nvec + BLOCK - 1) / BLOCK;
    init_out<<<nblk, BLOCK, 0, stream>>>(hist, out, out_size);

    // 2) accumulate batch histogram
    int nslices = in_sizes[0] / SLICE_ELEMS;          // 32*12 = 384
    hist_kernel<<<nslices * SPLIT, BLOCK, 0, stream>>>(x, out);
}

// Round 2
// 148.779 us; speedup vs baseline: 1.0129x; 1.0099x over previous
//
#include <hip/hip_runtime.h>

#define NCHAN 12
#define NBINS 2200
#define HMIN  (-1200.0f)
#define HMAX  (1000.0f)
#define SLICE_ELEMS 65536      // 256*256, one (batch, channel) slab
#define SPLIT 4                // blocks per slab -> 1536 blocks = 6/CU, 24 waves/CU
#define BLOCK 256

// Kernel 1: out = hist_counts (WRITE, not add — d_out is poisoned 0xAA).
// float4-vectorized; scalar tail for generality.
__global__ __launch_bounds__(BLOCK)
void init_out(const float* __restrict__ hist, float* __restrict__ out, int n) {
    int i = (blockIdx.x * BLOCK + threadIdx.x) * 4;
    if (i + 3 < n) {
        *(float4*)(out + i) = *(const float4*)(hist + i);
    } else {
        for (; i < n; ++i) out[i] = hist[i];
    }
}

__device__ __forceinline__ void bin4(const float4 v, unsigned int* lh) {
    float vals[4] = {v.x, v.y, v.z, v.w};
#pragma unroll
    for (int j = 0; j < 4; ++j) {
        // Bin width is exactly 1.0f (2200 bins over [-1200, 1000]), so
        // bin = floor(f + 1200).  For t >= 0, (int)t truncation == floor.
        // t >= 0.0f  <=>  f >= -1200.0f in fp32 (boundary rounding checked:
        // the largest fp32 below -1200 gives t = -1.22e-4, strictly < 0).
        // NaN fails t >= 0.  f == 1000 -> t = 2200 -> min -> last bin,
        // matching torch.histc.
        float t = vals[j] + 1200.0f;
        if (t >= 0.0f && vals[j] <= HMAX) {
            int idx = min((int)t, NBINS - 1);
            atomicAdd(&lh[idx], 1u);
        }
    }
}

// Kernel 2: per-block private LDS histogram over one slab chunk, then
// global float atomicAdd flush into out[c*NBINS + bin].
__global__ __launch_bounds__(BLOCK)
void hist_kernel(const float* __restrict__ x, float* __restrict__ out) {
    __shared__ unsigned int lh[NBINS];
    for (int i = threadIdx.x; i < NBINS; i += BLOCK) lh[i] = 0u;
    __syncthreads();

    const int slice = blockIdx.x / SPLIT;     // = b*NCHAN + c (layout [B,C,H,W])
    const int sub   = blockIdx.x % SPLIT;
    const int c     = slice % NCHAN;
    const int chunk = SLICE_ELEMS / SPLIT;    // 16384 elements per block

    const float4* __restrict__ xp =
        (const float4*)(x + (long long)slice * SLICE_ELEMS + (long long)sub * chunk);

    // chunk/4 = 4096 float4 = 2 outer iters x (256 threads x 8 loads).
    // Exact fit: 4096 == 2 * BLOCK * 8, so no bounds check needed.
    // Both iterations fully unrolled: 8 independent 16B loads in flight per
    // group, and the compiler can hoist iter-1 loads under iter-0 binning.
#pragma unroll
    for (int k = 0; k < 2; ++k) {
        const int base = threadIdx.x + k * (BLOCK * 8);
        float4 v[8];
#pragma unroll
        for (int u = 0; u < 8; ++u) v[u] = xp[base + u * BLOCK];
#pragma unroll
        for (int u = 0; u < 8; ++u) bin4(v[u], lh);
    }
    __syncthreads();

    float* __restrict__ outc = out + c * NBINS;
    for (int i = threadIdx.x; i < NBINS; i += BLOCK) {
        unsigned int v = lh[i];
        if (v) atomicAdd(&outc[i], (float)v);  // integer-valued, exact in fp32
    }
}

extern "C" void kernel_launch(void* const* d_in, const int* in_sizes, int n_in,
                              void* d_out, int out_size, void* d_ws, size_t ws_size,
                              hipStream_t stream) {
    const float* x    = (const float*)d_in[0];
    const float* hist = (const float*)d_in[1];
    float* out        = (float*)d_out;

    // 1) out = hist_counts  (out_size = 26400 elements; float4 path)
    int nvec = (out_size + 3) / 4;
    int nblk = (nvec + BLOCK - 1) / BLOCK;
    init_out<<<nblk, BLOCK, 0, stream>>>(hist, out, out_size);

    // 2) accumulate batch histogram
    int nslices = in_sizes[0] / SLICE_ELEMS;          // 32*12 = 384
    hist_kernel<<<nslices * SPLIT, BLOCK, 0, stream>>>(x, out);
}